// Round 16
// baseline (107.517 us; speedup 1.0000x reference)
//
#include <hip/hip_runtime.h>
#include <math.h>

#define BB 2
#define NPTS 1024
#define KK 64
#define NSZ 32
#define CC 1331      // 11^3
#define FF 32
#define RAD2 1.0f
#define NCOL 121     // 11*11 (ix,iy) columns
#define NRNG 4       // point ranges per batch (256 pts each)

// ---------------- K1: feature MLPs + score + tgt (x,y,z,|t|^2) + A-precompute ------
__global__ __launch_bounds__(64)
void k_features(const float* __restrict__ src_pts, const float* __restrict__ tgt_pts,
                const float* __restrict__ W1, const float* __restrict__ b1,
                const float* __restrict__ W2, const float* __restrict__ b2,
                const float* __restrict__ Ww1, const float* __restrict__ bw1,
                const float* __restrict__ Ww2, const float* __restrict__ bw2,
                const float* __restrict__ Wd1, const float* __restrict__ bd1,
                float* __restrict__ src_feat, float* __restrict__ tgt_A,
                float* __restrict__ tgt_m2, float* __restrict__ score)
{
    int gid = blockIdx.x * blockDim.x + threadIdx.x;   // 0..4095
    int isTgt = gid >= BB * NPTS;
    int pn = gid & (BB * NPTS - 1);
    int b = pn >> 10, n = pn & 1023;
    const float* pts = isTgt ? tgt_pts : src_pts;
    float p[6];
#pragma unroll
    for (int i = 0; i < 6; i++) p[i] = pts[(b * 6 + i) * NPTS + n];
    float h[FF];
#pragma unroll
    for (int j = 0; j < FF; j++) {
        float a = b1[j];
#pragma unroll
        for (int i = 0; i < 6; i++) a = fmaf(p[i], W1[i * FF + j], a);
        h[j] = fmaxf(a, 0.0f);
    }
    float ft[FF];
#pragma unroll
    for (int j = 0; j < FF; j++) {
        float a = b2[j];
#pragma unroll
        for (int i = 0; i < FF; i++) a = fmaf(h[i], W2[i * FF + j], a);
        ft[j] = fmaxf(a, 0.0f);
    }
    if (isTgt) {
        float x = p[0], y = p[1], z = p[2];
        float4 v; v.x = x; v.y = y; v.z = z; v.w = x * x + y * y + z * z;
        ((float4*)tgt_m2)[b * NPTS + n] = v;
        float av[FF];
#pragma unroll
        for (int j = 0; j < FF; j++) av[j] = bd1[j];
#pragma unroll
        for (int i = 0; i < FF; i++) {
            float fi = ft[i];
#pragma unroll
            for (int j = 0; j < FF; j++)
                av[j] = fmaf(fi, Wd1[(3 + i) * FF + j], av[j]);
        }
#pragma unroll
        for (int j = 0; j < FF; j++) tgt_A[(b * NPTS + n) * FF + j] = av[j];
    } else {
#pragma unroll
        for (int j = 0; j < FF; j++) src_feat[(b * NPTS + n) * FF + j] = ft[j];
        float acc = bw2[0];
#pragma unroll
        for (int j = 0; j < 16; j++) {
            float a = bw1[j];
#pragma unroll
            for (int i = 0; i < FF; i++) a = fmaf(ft[i], Ww1[i * 16 + j], a);
            acc = fmaf(fmaxf(a, 0.0f), Ww2[j], acc);
        }
        score[b * NPTS + n] = acc;
    }
}

// ---------------- K2: rank-based top-K (exact lax.top_k order) ----------------
__global__ __launch_bounds__(256)
void k_rank(const float* __restrict__ score, const float* __restrict__ src_pts,
            const float* __restrict__ R,
            int* __restrict__ key_idx, float* __restrict__ kxyz,
            float* __restrict__ kxyz_t, float* __restrict__ out_kxyz)
{
    int blk = blockIdx.x;            // 0..BB*16-1
    int b = blk >> 4;
    int pbase = (blk & 15) << 6;     // 64 points per block
    int t = threadIdx.x;
    int sub = t & 3;                 // j-partition 0..3
    int lp = t >> 2;                 // local point 0..63
    int n = pbase + lp;
    __shared__ float sc[NPTS];
    for (int i = t; i < NPTS; i += 256) sc[i] = score[b * NPTS + i];
    __syncthreads();
    float s = sc[n];
    int rank = 0;
#pragma unroll 8
    for (int jj = 0; jj < 256; jj++) {
        int j = (jj << 2) | sub;
        float sj = sc[j];
        bool before = (sj > s) || (sj == s && j < n);
        rank += before ? 1 : 0;
    }
    rank += __shfl_xor(rank, 1, 64);
    rank += __shfl_xor(rank, 2, 64);
    if (sub == 0 && rank < KK) {
        key_idx[b * KK + rank] = n;
        float x = src_pts[(b * 6 + 0) * NPTS + n];
        float y = src_pts[(b * 6 + 1) * NPTS + n];
        float z = src_pts[(b * 6 + 2) * NPTS + n];
        int o = (b * KK + rank) * 3;
        kxyz[o] = x; kxyz[o + 1] = y; kxyz[o + 2] = z;
        out_kxyz[o] = x; out_kxyz[o + 1] = y; out_kxyz[o + 2] = z;
#pragma unroll
        for (int i = 0; i < 3; i++)
            kxyz_t[o + i] = R[i * 3 + 0] * x + R[i * 3 + 1] * y + R[i * 3 + 2] * z;
    }
}

// ---------------- K3: separable NN scan, NRNG=4 (256-pt ranges) ----------------
__global__ __launch_bounds__(256)
void k_scan(const float* __restrict__ kxyz_t, const float* __restrict__ tgt_m2,
            float2* __restrict__ part)
{
    int bid = blockIdx.x;
    int bk = bid >> 2, r = bid & 3;
    int b = bk >> 6;
    int t = threadIdx.x;
    int u = t >> 7, lt = t & 127;
    __shared__ float4 P[256];            // 4 KB
    __shared__ float2 pbuf[2][NCOL][11]; // 21.3 KB
    P[t] = ((const float4*)tgt_m2)[(b << 10) + (r << 8) + t];
    float kx = kxyz_t[bk * 3 + 0], ky = kxyz_t[bk * 3 + 1], kz = kxyz_t[bk * 3 + 2];
    float kx2 = -2.0f * kx, ky2 = -2.0f * ky, kz2 = -2.0f * kz;
    bool active = lt < NCOL;
    int pc = active ? lt : 0;
    int ixv = pc / 11, iyv = pc - ixv * 11;
    float gx2 = -2.0f * (-2.0f + ixv * 0.4f);
    float gy2 = -2.0f * (-2.0f + iyv * 0.4f);
    float gz2[11];
#pragma unroll
    for (int iz = 0; iz < 11; iz++) gz2[iz] = -2.0f * (-2.0f + iz * 0.4f);
    float best[11]; int bn[11];
#pragma unroll
    for (int iz = 0; iz < 11; iz++) { best[iz] = 3.0e38f; bn[iz] = 0; }
    __syncthreads();
    if (active) {
        const int pb = u << 7;           // unit scans 128 points
#pragma unroll 8
        for (int i = 0; i < 128; i++) {
            float4 v = P[pb + i];        // wave-uniform addr -> LDS broadcast
            float a = fmaf(kx2, v.x, fmaf(ky2, v.y, fmaf(kz2, v.z, v.w)));
            float e = fmaf(gx2, v.x, fmaf(gy2, v.y, a));
#pragma unroll
            for (int iz = 0; iz < 11; iz++) {
                float d = fmaf(gz2[iz], v.z, e);
                bool l = d < best[iz];   // strict <: first-min in scan order
                best[iz] = l ? d : best[iz];
                bn[iz] = l ? i : bn[iz];
            }
        }
#pragma unroll
        for (int iz = 0; iz < 11; iz++)
            pbuf[u][lt][iz] = make_float2(best[iz], __int_as_float(bn[iz] + (u << 7)));
    }
    __syncthreads();
    if (u == 0 && active) {
        int cbase = ((bk << 2) + r) * CC + lt * 11;  // c = p*11 + iz (contiguous)
#pragma unroll
        for (int iz = 0; iz < 11; iz++) {
            float2 r0 = pbuf[0][lt][iz], r1 = pbuf[1][lt][iz];
            float2 m = (r1.x < r0.x) ? r1 : r0;      // tie -> unit 0 = lower points
            part[cbase + iz] = make_float2(m.x,
                __int_as_float(__float_as_int(m.y) + (r << 8)));
        }
    }
}

// ---------------- K4: fused gemb + merge + mlp + last-block softmax ----------------
// 768 blocks x 256 thr. Per block: recompute bk's src_emb in LDS (verbatim),
// thread-per-candidate merge->dfe->sim, then completion-counter; 6th block per bk
// runs the softmax (verbatim k_softmax body, 256-thread order) over sim.
__global__ __launch_bounds__(256)
void k_mlp(const float2* __restrict__ part, const float* __restrict__ kxyz_t,
           const float* __restrict__ kxyz, const int* __restrict__ key_idx,
           const float* __restrict__ src_feat,
           const float* __restrict__ tgt_m2, const float* __restrict__ tgt_A,
           const float* __restrict__ Wd1, const float* __restrict__ bd1,
           const float* __restrict__ Wd2, const float* __restrict__ bd2,
           float* __restrict__ sim, unsigned* __restrict__ cnt,
           float* __restrict__ out_vcp)
{
    const int NCH = 6;                   // ceil(1331/256)
    int bid = blockIdx.x;
    int chunk = bid % NCH;
    int bk = bid / NCH;
    int b = bk >> 6, kk = bk & 63;
    int t = threadIdx.x;
    __shared__ float kxs[KK][3];
    __shared__ int gidx[NSZ];
    __shared__ float hb[NSZ][FF + 1];    // +1 pad: avoid bank alias on layer-2 reads
    __shared__ float eb[NSZ][FF + 1];
    __shared__ float semb[FF];
    __shared__ unsigned lastflag;
    __shared__ float red[256];
    __shared__ float4 red4[256];
    if (t < KK) {
        kxs[t][0] = kxyz[(b * KK + t) * 3 + 0];
        kxs[t][1] = kxyz[(b * KK + t) * 3 + 1];
        kxs[t][2] = kxyz[(b * KK + t) * 3 + 2];
    }
    __syncthreads();
    if (t < KK) {                        // wave 0: ballot grouping (verbatim gemb)
        float cx = kxs[kk][0], cy = kxs[kk][1], cz = kxs[kk][2];
        float dx = kxs[t][0] - cx, dy = kxs[t][1] - cy, dz = kxs[t][2] - cz;
        float sq = dx * dx + dy * dy + dz * dz;
        unsigned long long mask = __ballot(sq <= RAD2);
        if (t < NSZ) {
            int cnt2 = __popcll(mask);
            int want = (t < cnt2) ? t : 0;
            unsigned long long mm = mask;
            for (int q = 0; q < want; q++) mm &= (mm - 1);
            gidx[t] = __ffsll(mm) - 1;
        }
    }
    __syncthreads();
    {   // layer 1: 256 thr = 32 neighbors x 8 j-groups of 4
        int s = t >> 3, jb = (t & 7) << 2;
        int g = gidx[s];
        float cx = kxs[kk][0], cy = kxs[kk][1], cz = kxs[kk][2];
        float xr = kxs[g][0] - cx, yr = kxs[g][1] - cy, zr = kxs[g][2] - cz;
        int orig = key_idx[b * KK + g];
        const float* fz = &src_feat[(b * NPTS + orig) * FF];
        float fr[FF];
#pragma unroll
        for (int i = 0; i < FF; i++) fr[i] = fz[i];
#pragma unroll
        for (int jj = 0; jj < 4; jj++) {
            int j = jb + jj;
            float a = bd1[j];
            a = fmaf(xr, Wd1[0 * FF + j], a);
            a = fmaf(yr, Wd1[1 * FF + j], a);
            a = fmaf(zr, Wd1[2 * FF + j], a);
#pragma unroll
            for (int i = 0; i < FF; i++) a = fmaf(fr[i], Wd1[(3 + i) * FF + j], a);
            hb[s][j] = fmaxf(a, 0.0f);
        }
    }
    __syncthreads();
    {   // layer 2
        int s = t >> 3, jb = (t & 7) << 2;
#pragma unroll
        for (int jj = 0; jj < 4; jj++) {
            int j = jb + jj;
            float a = bd2[j];
#pragma unroll
            for (int i = 0; i < FF; i++) a = fmaf(hb[s][i], Wd2[i * FF + j], a);
            eb[s][j] = fmaxf(a, 0.0f);
        }
    }
    __syncthreads();
    if (t < FF) {                        // maxpool, ascending s (matches gemb)
        float m = eb[0][t];
#pragma unroll
        for (int s2 = 1; s2 < NSZ; s2++) m = fmaxf(m, eb[s2][t]);
        semb[t] = m;
    }
    __syncthreads();
    // ---------------- candidate phase (round-15 verbatim) ----------
    int c = chunk * 256 + t;
    int cc = min(c, CC - 1);
    float2 rb = part[(bk << 2) * CC + cc];
#pragma unroll
    for (int r = 1; r < NRNG; r++) {
        float2 o = part[((bk << 2) + r) * CC + cc];
        if (o.x < rb.x) rb = o;          // ascending r, strict <
    }
    int nb = __float_as_int(rb.y);
    float4 nv = ((const float4*)tgt_m2)[(b << 10) + nb];
    const float4* az = (const float4*)&tgt_A[((b << 10) + nb) * FF];
    float h[FF];
#pragma unroll
    for (int i = 0; i < FF / 4; i++) {
        float4 v = az[i];
        h[i * 4 + 0] = v.x; h[i * 4 + 1] = v.y; h[i * 4 + 2] = v.z; h[i * 4 + 3] = v.w;
    }
    int ixv = cc / 121, rem = cc - ixv * 121, iyv = rem / 11, izv = rem - iyv * 11;
    float cx2 = kxyz_t[bk * 3 + 0] + (-2.0f + ixv * 0.4f);
    float cy2 = kxyz_t[bk * 3 + 1] + (-2.0f + iyv * 0.4f);
    float cz2 = kxyz_t[bk * 3 + 2] + (-2.0f + izv * 0.4f);
    float x0 = cx2 - nv.x, x1 = cy2 - nv.y, x2 = cz2 - nv.z;
#pragma unroll
    for (int j = 0; j < FF; j++) {
        float a = h[j];
        a = fmaf(x0, Wd1[0 * FF + j], a);
        a = fmaf(x1, Wd1[1 * FF + j], a);
        a = fmaf(x2, Wd1[2 * FF + j], a);
        h[j] = fmaxf(a, 0.0f);
    }
    float sv = 0.0f;
#pragma unroll
    for (int j = 0; j < FF; j++) {
        float a = bd2[j];
#pragma unroll
        for (int i = 0; i < FF; i++) a = fmaf(h[i], Wd2[i * FF + j], a);
        sv = fmaf(fmaxf(a, 0.0f), semb[j], sv);
    }
    if (c < CC) sim[bk * CC + c] = sv;
    // ---------------- completion counter: 6th block per bk runs softmax ----------
    __syncthreads();                     // all sim writes of this block issued
    if (t == 0) {
        __threadfence();                 // release sim writes (device scope)
        lastflag = atomicAdd(&cnt[bk], 1u);
    }
    __syncthreads();
    if (lastflag != NCH - 1) return;     // not the last block for this bk
    __threadfence();                     // acquire other blocks' sim writes
    // verbatim k_softmax body (256-thread order -> bitwise-identical result)
    float kx = kxyz_t[bk * 3 + 0], ky = kxyz_t[bk * 3 + 1], kz = kxyz_t[bk * 3 + 2];
    float lm = -3.0e38f;
    for (int c2 = t; c2 < CC; c2 += 256) lm = fmaxf(lm, sim[bk * CC + c2]);
    red[t] = lm;
    __syncthreads();
    for (int s2 = 128; s2 > 0; s2 >>= 1) {
        if (t < s2) red[t] = fmaxf(red[t], red[t + s2]);
        __syncthreads();
    }
    float m = red[0];
    float se = 0.f, sx = 0.f, sy = 0.f, sz = 0.f;
    for (int c2 = t; c2 < CC; c2 += 256) {
        float e = expf(sim[bk * CC + c2] - m);
        int ix = c2 / 121, rem2 = c2 - ix * 121, iy = rem2 / 11, iz = rem2 - iy * 11;
        float cxx = kx + (-2.0f + ix * 0.4f);
        float cyy = ky + (-2.0f + iy * 0.4f);
        float czz = kz + (-2.0f + iz * 0.4f);
        se += e;
        sx = fmaf(e, cxx, sx);
        sy = fmaf(e, cyy, sy);
        sz = fmaf(e, czz, sz);
    }
    red4[t] = make_float4(se, sx, sy, sz);
    __syncthreads();
    for (int s2 = 128; s2 > 0; s2 >>= 1) {
        if (t < s2) {
            float4 a = red4[t], bq = red4[t + s2];
            red4[t] = make_float4(a.x + bq.x, a.y + bq.y, a.z + bq.z, a.w + bq.w);
        }
        __syncthreads();
    }
    if (t == 0) {
        float4 r = red4[0];
        out_vcp[bk * 3 + 0] = r.y / r.x;
        out_vcp[bk * 3 + 1] = r.z / r.x;
        out_vcp[bk * 3 + 2] = r.w / r.x;
    }
}

extern "C" void kernel_launch(void* const* d_in, const int* in_sizes, int n_in,
                              void* d_out, int out_size, void* d_ws, size_t ws_size,
                              hipStream_t stream)
{
    (void)in_sizes; (void)n_in; (void)out_size; (void)ws_size;
    const float* src_pts = (const float*)d_in[0];
    const float* tgt_pts = (const float*)d_in[1];
    const float* R_init  = (const float*)d_in[2];
    const float* W1  = (const float*)d_in[4];
    const float* b1  = (const float*)d_in[5];
    const float* W2  = (const float*)d_in[6];
    const float* b2  = (const float*)d_in[7];
    const float* Ww1 = (const float*)d_in[8];
    const float* bw1 = (const float*)d_in[9];
    const float* Ww2 = (const float*)d_in[10];
    const float* bw2 = (const float*)d_in[11];
    const float* Wd1 = (const float*)d_in[12];
    const float* bd1 = (const float*)d_in[13];
    const float* Wd2 = (const float*)d_in[14];
    const float* bd2 = (const float*)d_in[15];

    float* ws = (float*)d_ws;
    float* src_feat = ws;                              // 65536
    float* tgt_A    = src_feat + BB * NPTS * FF;       // 65536
    float* tgt_m2   = tgt_A + BB * NPTS * FF;          // 8192
    float* score    = tgt_m2 + BB * NPTS * 4;          // 2048
    int*   key_idx  = (int*)(score + BB * NPTS);       // 128
    float* kxyz     = (float*)(key_idx + BB * KK);     // 384
    float* kxyz_t   = kxyz + BB * KK * 3;              // 384
    float* sim      = kxyz_t + BB * KK * 3;            // 170368
    float2* part    = (float2*)(sim + BB * KK * CC);   // 128*4*1331 float2 = 5.45 MB
    unsigned* cnt   = (unsigned*)(part + BB * KK * NRNG * CC); // 128 counters

    float* out_kxyz = (float*)d_out;
    float* out_vcp  = out_kxyz + BB * KK * 3;

    hipMemsetAsync(cnt, 0, BB * KK * sizeof(unsigned), stream);
    k_features<<<64, 64, 0, stream>>>(
        src_pts, tgt_pts, W1, b1, W2, b2, Ww1, bw1, Ww2, bw2, Wd1, bd1,
        src_feat, tgt_A, tgt_m2, score);
    k_rank<<<BB * 16, 256, 0, stream>>>(score, src_pts, R_init,
                                        key_idx, kxyz, kxyz_t, out_kxyz);
    k_scan<<<BB * KK * NRNG, 256, 0, stream>>>(kxyz_t, tgt_m2, part);
    k_mlp<<<BB * KK * 6, 256, 0, stream>>>(part, kxyz_t, kxyz, key_idx, src_feat,
                                           tgt_m2, tgt_A, Wd1, bd1, Wd2, bd2,
                                           sim, cnt, out_vcp);
}

// Round 17
// 66.268 us; speedup vs baseline: 1.6225x; 1.6225x over previous
//
#include <hip/hip_runtime.h>
#include <math.h>

#define BB 2
#define NPTS 1024
#define KK 64
#define NSZ 32
#define CC 1331      // 11^3
#define FF 32
#define RAD2 1.0f
#define NCOL 121     // 11*11 (ix,iy) columns
#define NRNG 4       // point ranges per batch (256 pts each)

// ---------------- K1: feature MLPs + score + tgt (x,y,z,|t|^2) + A-precompute ------
__global__ __launch_bounds__(64)
void k_features(const float* __restrict__ src_pts, const float* __restrict__ tgt_pts,
                const float* __restrict__ W1, const float* __restrict__ b1,
                const float* __restrict__ W2, const float* __restrict__ b2,
                const float* __restrict__ Ww1, const float* __restrict__ bw1,
                const float* __restrict__ Ww2, const float* __restrict__ bw2,
                const float* __restrict__ Wd1, const float* __restrict__ bd1,
                float* __restrict__ src_feat, float* __restrict__ tgt_A,
                float* __restrict__ tgt_m2, float* __restrict__ score)
{
    int gid = blockIdx.x * blockDim.x + threadIdx.x;   // 0..4095
    int isTgt = gid >= BB * NPTS;
    int pn = gid & (BB * NPTS - 1);
    int b = pn >> 10, n = pn & 1023;
    const float* pts = isTgt ? tgt_pts : src_pts;
    float p[6];
#pragma unroll
    for (int i = 0; i < 6; i++) p[i] = pts[(b * 6 + i) * NPTS + n];
    float h[FF];
#pragma unroll
    for (int j = 0; j < FF; j++) {
        float a = b1[j];
#pragma unroll
        for (int i = 0; i < 6; i++) a = fmaf(p[i], W1[i * FF + j], a);
        h[j] = fmaxf(a, 0.0f);
    }
    float ft[FF];
#pragma unroll
    for (int j = 0; j < FF; j++) {
        float a = b2[j];
#pragma unroll
        for (int i = 0; i < FF; i++) a = fmaf(h[i], W2[i * FF + j], a);
        ft[j] = fmaxf(a, 0.0f);
    }
    if (isTgt) {
        float x = p[0], y = p[1], z = p[2];
        float4 v; v.x = x; v.y = y; v.z = z; v.w = x * x + y * y + z * z;
        ((float4*)tgt_m2)[b * NPTS + n] = v;
        float av[FF];
#pragma unroll
        for (int j = 0; j < FF; j++) av[j] = bd1[j];
#pragma unroll
        for (int i = 0; i < FF; i++) {
            float fi = ft[i];
#pragma unroll
            for (int j = 0; j < FF; j++)
                av[j] = fmaf(fi, Wd1[(3 + i) * FF + j], av[j]);
        }
#pragma unroll
        for (int j = 0; j < FF; j++) tgt_A[(b * NPTS + n) * FF + j] = av[j];
    } else {
#pragma unroll
        for (int j = 0; j < FF; j++) src_feat[(b * NPTS + n) * FF + j] = ft[j];
        float acc = bw2[0];
#pragma unroll
        for (int j = 0; j < 16; j++) {
            float a = bw1[j];
#pragma unroll
            for (int i = 0; i < FF; i++) a = fmaf(ft[i], Ww1[i * 16 + j], a);
            acc = fmaf(fmaxf(a, 0.0f), Ww2[j], acc);
        }
        score[b * NPTS + n] = acc;
    }
}

// ---------------- K2: rank-based top-K (exact lax.top_k order) ----------------
__global__ __launch_bounds__(256)
void k_rank(const float* __restrict__ score, const float* __restrict__ src_pts,
            const float* __restrict__ R,
            int* __restrict__ key_idx, float* __restrict__ kxyz,
            float* __restrict__ kxyz_t, float* __restrict__ out_kxyz)
{
    int blk = blockIdx.x;            // 0..BB*16-1
    int b = blk >> 4;
    int pbase = (blk & 15) << 6;     // 64 points per block
    int t = threadIdx.x;
    int sub = t & 3;                 // j-partition 0..3
    int lp = t >> 2;                 // local point 0..63
    int n = pbase + lp;
    __shared__ float sc[NPTS];
    for (int i = t; i < NPTS; i += 256) sc[i] = score[b * NPTS + i];
    __syncthreads();
    float s = sc[n];
    int rank = 0;
#pragma unroll 8
    for (int jj = 0; jj < 256; jj++) {
        int j = (jj << 2) | sub;
        float sj = sc[j];
        bool before = (sj > s) || (sj == s && j < n);
        rank += before ? 1 : 0;
    }
    rank += __shfl_xor(rank, 1, 64);
    rank += __shfl_xor(rank, 2, 64);
    if (sub == 0 && rank < KK) {
        key_idx[b * KK + rank] = n;
        float x = src_pts[(b * 6 + 0) * NPTS + n];
        float y = src_pts[(b * 6 + 1) * NPTS + n];
        float z = src_pts[(b * 6 + 2) * NPTS + n];
        int o = (b * KK + rank) * 3;
        kxyz[o] = x; kxyz[o + 1] = y; kxyz[o + 2] = z;
        out_kxyz[o] = x; out_kxyz[o + 1] = y; out_kxyz[o + 2] = z;
#pragma unroll
        for (int i = 0; i < 3; i++)
            kxyz_t[o + i] = R[i * 3 + 0] * x + R[i * 3 + 1] * y + R[i * 3 + 2] * z;
    }
}

// ---------------- K3: separable NN scan + gemb tail on r==0 blocks ----------------
// grid = 128 bk x 4 ranges. Block = 256 thr = 2 units x 128 (121 active);
// unit u scans 128 points. part[(bk*4+r)*CC + c] = (best d', global point idx);
// merge order (r asc, u asc, i asc) == point order -> exact argmin semantics.
// r==0 blocks then compute bk's src_emb (verbatim gemb, single producer).
__global__ __launch_bounds__(256)
void k_scan(const float* __restrict__ kxyz_t, const float* __restrict__ tgt_m2,
            const float* __restrict__ kxyz, const int* __restrict__ key_idx,
            const float* __restrict__ src_feat,
            const float* __restrict__ Wd1, const float* __restrict__ bd1,
            const float* __restrict__ Wd2, const float* __restrict__ bd2,
            float2* __restrict__ part, float* __restrict__ src_emb)
{
    int bid = blockIdx.x;
    int bk = bid >> 2, r = bid & 3;
    int b = bk >> 6, kk = bk & 63;
    int t = threadIdx.x;
    int u = t >> 7, lt = t & 127;
    __shared__ float4 P[256];            // 4 KB
    __shared__ float2 pbuf[2][NCOL][11]; // 21.3 KB
    __shared__ float kxs[KK][3];
    __shared__ int gidx[NSZ];
    __shared__ float hb[NSZ][FF + 1];    // +1 pad
    __shared__ float eb[NSZ][FF + 1];
    P[t] = ((const float4*)tgt_m2)[(b << 10) + (r << 8) + t];
    float kx = kxyz_t[bk * 3 + 0], ky = kxyz_t[bk * 3 + 1], kz = kxyz_t[bk * 3 + 2];
    float kx2 = -2.0f * kx, ky2 = -2.0f * ky, kz2 = -2.0f * kz;
    bool active = lt < NCOL;
    int pc = active ? lt : 0;
    int ixv = pc / 11, iyv = pc - ixv * 11;
    float gx2 = -2.0f * (-2.0f + ixv * 0.4f);
    float gy2 = -2.0f * (-2.0f + iyv * 0.4f);
    float gz2[11];
#pragma unroll
    for (int iz = 0; iz < 11; iz++) gz2[iz] = -2.0f * (-2.0f + iz * 0.4f);
    float best[11]; int bn[11];
#pragma unroll
    for (int iz = 0; iz < 11; iz++) { best[iz] = 3.0e38f; bn[iz] = 0; }
    __syncthreads();
    if (active) {
        const int pb = u << 7;           // unit scans 128 points
#pragma unroll 8
        for (int i = 0; i < 128; i++) {
            float4 v = P[pb + i];        // wave-uniform addr -> LDS broadcast
            float a = fmaf(kx2, v.x, fmaf(ky2, v.y, fmaf(kz2, v.z, v.w)));
            float e = fmaf(gx2, v.x, fmaf(gy2, v.y, a));
#pragma unroll
            for (int iz = 0; iz < 11; iz++) {
                float d = fmaf(gz2[iz], v.z, e);
                bool l = d < best[iz];   // strict <: first-min in scan order
                best[iz] = l ? d : best[iz];
                bn[iz] = l ? i : bn[iz];
            }
        }
#pragma unroll
        for (int iz = 0; iz < 11; iz++)
            pbuf[u][lt][iz] = make_float2(best[iz], __int_as_float(bn[iz] + (u << 7)));
    }
    __syncthreads();
    if (u == 0 && active) {
        int cbase = ((bk << 2) + r) * CC + lt * 11;  // c = p*11 + iz (contiguous)
#pragma unroll
        for (int iz = 0; iz < 11; iz++) {
            float2 r0 = pbuf[0][lt][iz], r1 = pbuf[1][lt][iz];
            float2 m = (r1.x < r0.x) ? r1 : r0;      // tie -> unit 0 = lower points
            part[cbase + iz] = make_float2(m.x,
                __int_as_float(__float_as_int(m.y) + (r << 8)));
        }
    }
    if (r != 0) return;                  // block-uniform: barriers below are safe
    // ---------------- gemb tail (verbatim round-15 prelude, single producer) ------
    if (t < KK) {
        kxs[t][0] = kxyz[(b * KK + t) * 3 + 0];
        kxs[t][1] = kxyz[(b * KK + t) * 3 + 1];
        kxs[t][2] = kxyz[(b * KK + t) * 3 + 2];
    }
    __syncthreads();
    if (t < KK) {                        // wave 0: ballot grouping
        float cx = kxs[kk][0], cy = kxs[kk][1], cz = kxs[kk][2];
        float dx = kxs[t][0] - cx, dy = kxs[t][1] - cy, dz = kxs[t][2] - cz;
        float sq = dx * dx + dy * dy + dz * dz;
        unsigned long long mask = __ballot(sq <= RAD2);
        if (t < NSZ) {
            int cnt = __popcll(mask);
            int want = (t < cnt) ? t : 0;
            unsigned long long mm = mask;
            for (int q = 0; q < want; q++) mm &= (mm - 1);
            gidx[t] = __ffsll(mm) - 1;
        }
    }
    __syncthreads();
    {   // layer 1: 256 thr = 32 neighbors x 8 j-groups of 4
        int s = t >> 3, jb = (t & 7) << 2;
        int g = gidx[s];
        float cx = kxs[kk][0], cy = kxs[kk][1], cz = kxs[kk][2];
        float xr = kxs[g][0] - cx, yr = kxs[g][1] - cy, zr = kxs[g][2] - cz;
        int orig = key_idx[b * KK + g];
        const float* fz = &src_feat[(b * NPTS + orig) * FF];
        float fr[FF];
#pragma unroll
        for (int i = 0; i < FF; i++) fr[i] = fz[i];
#pragma unroll
        for (int jj = 0; jj < 4; jj++) {
            int j = jb + jj;
            float a = bd1[j];
            a = fmaf(xr, Wd1[0 * FF + j], a);
            a = fmaf(yr, Wd1[1 * FF + j], a);
            a = fmaf(zr, Wd1[2 * FF + j], a);
#pragma unroll
            for (int i = 0; i < FF; i++) a = fmaf(fr[i], Wd1[(3 + i) * FF + j], a);
            hb[s][j] = fmaxf(a, 0.0f);
        }
    }
    __syncthreads();
    {   // layer 2
        int s = t >> 3, jb = (t & 7) << 2;
#pragma unroll
        for (int jj = 0; jj < 4; jj++) {
            int j = jb + jj;
            float a = bd2[j];
#pragma unroll
            for (int i = 0; i < FF; i++) a = fmaf(hb[s][i], Wd2[i * FF + j], a);
            eb[s][j] = fmaxf(a, 0.0f);
        }
    }
    __syncthreads();
    if (t < FF) {                        // maxpool, ascending s (matches gemb)
        float m = eb[0][t];
#pragma unroll
        for (int s2 = 1; s2 < NSZ; s2++) m = fmaxf(m, eb[s2][t]);
        src_emb[bk * FF + t] = m;
    }
}

// ---------------- K4: merge 4 partials -> gather A -> slim dfe -> sim ----------------
// 768 blocks x 256 thr, thread-per-candidate, all-static indexing; src_emb via
// uniform scalar loads (round-12-proven pattern).
__global__ __launch_bounds__(256)
void k_mlp(const float2* __restrict__ part, const float* __restrict__ kxyz_t,
           const float* __restrict__ tgt_m2, const float* __restrict__ tgt_A,
           const float* __restrict__ src_emb,
           const float* __restrict__ Wd1,
           const float* __restrict__ Wd2, const float* __restrict__ bd2,
           float* __restrict__ sim)
{
    const int NCH = 6;                   // ceil(1331/256)
    int bid = blockIdx.x;
    int chunk = bid % NCH;
    int bk = bid / NCH;
    int b = bk >> 6;
    int t = threadIdx.x;
    int c = chunk * 256 + t;
    int cc = min(c, CC - 1);
    float2 rb = part[(bk << 2) * CC + cc];
#pragma unroll
    for (int r = 1; r < NRNG; r++) {
        float2 o = part[((bk << 2) + r) * CC + cc];
        if (o.x < rb.x) rb = o;          // ascending r, strict <
    }
    int nb = __float_as_int(rb.y);
    float4 nv = ((const float4*)tgt_m2)[(b << 10) + nb];
    const float4* az = (const float4*)&tgt_A[((b << 10) + nb) * FF];
    float h[FF];
#pragma unroll
    for (int i = 0; i < FF / 4; i++) {
        float4 v = az[i];
        h[i * 4 + 0] = v.x; h[i * 4 + 1] = v.y; h[i * 4 + 2] = v.z; h[i * 4 + 3] = v.w;
    }
    int ixv = cc / 121, rem = cc - ixv * 121, iyv = rem / 11, izv = rem - iyv * 11;
    float cx = kxyz_t[bk * 3 + 0] + (-2.0f + ixv * 0.4f);
    float cy = kxyz_t[bk * 3 + 1] + (-2.0f + iyv * 0.4f);
    float cz = kxyz_t[bk * 3 + 2] + (-2.0f + izv * 0.4f);
    float x0 = cx - nv.x, x1 = cy - nv.y, x2 = cz - nv.z;
#pragma unroll
    for (int j = 0; j < FF; j++) {
        float a = h[j];
        a = fmaf(x0, Wd1[0 * FF + j], a);
        a = fmaf(x1, Wd1[1 * FF + j], a);
        a = fmaf(x2, Wd1[2 * FF + j], a);
        h[j] = fmaxf(a, 0.0f);
    }
    float sv = 0.0f;
#pragma unroll
    for (int j = 0; j < FF; j++) {
        float a = bd2[j];
#pragma unroll
        for (int i = 0; i < FF; i++) a = fmaf(h[i], Wd2[i * FF + j], a);
        sv = fmaf(fmaxf(a, 0.0f), src_emb[bk * FF + j], sv);
    }
    if (c < CC) sim[bk * CC + c] = sv;
}

// ---------------- K5: softmax over candidates + weighted sum ----------------
__global__ __launch_bounds__(256)
void k_softmax(const float* __restrict__ sim, const float* __restrict__ kxyz_t,
               float* __restrict__ out_vcp)
{
    int bk = blockIdx.x;
    int t = threadIdx.x;
    __shared__ float red[256];
    __shared__ float4 red4[256];
    float kx = kxyz_t[bk * 3 + 0], ky = kxyz_t[bk * 3 + 1], kz = kxyz_t[bk * 3 + 2];
    float lm = -3.0e38f;
    for (int c = t; c < CC; c += 256) lm = fmaxf(lm, sim[bk * CC + c]);
    red[t] = lm;
    __syncthreads();
    for (int s2 = 128; s2 > 0; s2 >>= 1) {
        if (t < s2) red[t] = fmaxf(red[t], red[t + s2]);
        __syncthreads();
    }
    float m = red[0];
    float se = 0.f, sx = 0.f, sy = 0.f, sz = 0.f;
    for (int c = t; c < CC; c += 256) {
        float e = expf(sim[bk * CC + c] - m);
        int ix = c / 121, rem = c - ix * 121, iy = rem / 11, iz = rem - iy * 11;
        float cxx = kx + (-2.0f + ix * 0.4f);
        float cyy = ky + (-2.0f + iy * 0.4f);
        float czz = kz + (-2.0f + iz * 0.4f);
        se += e;
        sx = fmaf(e, cxx, sx);
        sy = fmaf(e, cyy, sy);
        sz = fmaf(e, czz, sz);
    }
    red4[t] = make_float4(se, sx, sy, sz);
    __syncthreads();
    for (int s2 = 128; s2 > 0; s2 >>= 1) {
        if (t < s2) {
            float4 a = red4[t], bq = red4[t + s2];
            red4[t] = make_float4(a.x + bq.x, a.y + bq.y, a.z + bq.z, a.w + bq.w);
        }
        __syncthreads();
    }
    if (t == 0) {
        float4 r = red4[0];
        out_vcp[bk * 3 + 0] = r.y / r.x;
        out_vcp[bk * 3 + 1] = r.z / r.x;
        out_vcp[bk * 3 + 2] = r.w / r.x;
    }
}

extern "C" void kernel_launch(void* const* d_in, const int* in_sizes, int n_in,
                              void* d_out, int out_size, void* d_ws, size_t ws_size,
                              hipStream_t stream)
{
    (void)in_sizes; (void)n_in; (void)out_size; (void)ws_size;
    const float* src_pts = (const float*)d_in[0];
    const float* tgt_pts = (const float*)d_in[1];
    const float* R_init  = (const float*)d_in[2];
    const float* W1  = (const float*)d_in[4];
    const float* b1  = (const float*)d_in[5];
    const float* W2  = (const float*)d_in[6];
    const float* b2  = (const float*)d_in[7];
    const float* Ww1 = (const float*)d_in[8];
    const float* bw1 = (const float*)d_in[9];
    const float* Ww2 = (const float*)d_in[10];
    const float* bw2 = (const float*)d_in[11];
    const float* Wd1 = (const float*)d_in[12];
    const float* bd1 = (const float*)d_in[13];
    const float* Wd2 = (const float*)d_in[14];
    const float* bd2 = (const float*)d_in[15];

    float* ws = (float*)d_ws;
    float* src_feat = ws;                              // 65536
    float* tgt_A    = src_feat + BB * NPTS * FF;       // 65536
    float* tgt_m2   = tgt_A + BB * NPTS * FF;          // 8192
    float* score    = tgt_m2 + BB * NPTS * 4;          // 2048
    int*   key_idx  = (int*)(score + BB * NPTS);       // 128
    float* kxyz     = (float*)(key_idx + BB * KK);     // 384
    float* kxyz_t   = kxyz + BB * KK * 3;              // 384
    float* src_emb  = kxyz_t + BB * KK * 3;            // 4096
    float* sim      = src_emb + BB * KK * FF;          // 170368
    float2* part    = (float2*)(sim + BB * KK * CC);   // 128*4*1331 float2 = 5.45 MB

    float* out_kxyz = (float*)d_out;
    float* out_vcp  = out_kxyz + BB * KK * 3;

    k_features<<<64, 64, 0, stream>>>(
        src_pts, tgt_pts, W1, b1, W2, b2, Ww1, bw1, Ww2, bw2, Wd1, bd1,
        src_feat, tgt_A, tgt_m2, score);
    k_rank<<<BB * 16, 256, 0, stream>>>(score, src_pts, R_init,
                                        key_idx, kxyz, kxyz_t, out_kxyz);
    k_scan<<<BB * KK * NRNG, 256, 0, stream>>>(kxyz_t, tgt_m2, kxyz, key_idx,
                                               src_feat, Wd1, bd1, Wd2, bd2,
                                               part, src_emb);
    k_mlp<<<BB * KK * 6, 256, 0, stream>>>(part, kxyz_t, tgt_m2, tgt_A, src_emb,
                                           Wd1, Wd2, bd2, sim);
    k_softmax<<<BB * KK, 256, 0, stream>>>(sim, kxyz_t, out_vcp);
}

// Round 18
// 63.519 us; speedup vs baseline: 1.6927x; 1.0433x over previous
//
#include <hip/hip_runtime.h>
#include <math.h>

#define BB 2
#define NPTS 1024
#define KK 64
#define NSZ 32
#define CC 1331      // 11^3
#define FF 32
#define RAD2 1.0f
#define NCOL 121     // 11*11 (ix,iy) columns
#define NRNG 4       // point ranges per batch (256 pts each)
#define NCH 6        // candidate chunks per bk (ceil(1331/256))

// ---------------- K1: feature MLPs + score + tgt (x,y,z,|t|^2) + A-precompute ------
__global__ __launch_bounds__(64)
void k_features(const float* __restrict__ src_pts, const float* __restrict__ tgt_pts,
                const float* __restrict__ W1, const float* __restrict__ b1,
                const float* __restrict__ W2, const float* __restrict__ b2,
                const float* __restrict__ Ww1, const float* __restrict__ bw1,
                const float* __restrict__ Ww2, const float* __restrict__ bw2,
                const float* __restrict__ Wd1, const float* __restrict__ bd1,
                float* __restrict__ src_feat, float* __restrict__ tgt_A,
                float* __restrict__ tgt_m2, float* __restrict__ score)
{
    int gid = blockIdx.x * blockDim.x + threadIdx.x;   // 0..4095
    int isTgt = gid >= BB * NPTS;
    int pn = gid & (BB * NPTS - 1);
    int b = pn >> 10, n = pn & 1023;
    const float* pts = isTgt ? tgt_pts : src_pts;
    float p[6];
#pragma unroll
    for (int i = 0; i < 6; i++) p[i] = pts[(b * 6 + i) * NPTS + n];
    float h[FF];
#pragma unroll
    for (int j = 0; j < FF; j++) {
        float a = b1[j];
#pragma unroll
        for (int i = 0; i < 6; i++) a = fmaf(p[i], W1[i * FF + j], a);
        h[j] = fmaxf(a, 0.0f);
    }
    float ft[FF];
#pragma unroll
    for (int j = 0; j < FF; j++) {
        float a = b2[j];
#pragma unroll
        for (int i = 0; i < FF; i++) a = fmaf(h[i], W2[i * FF + j], a);
        ft[j] = fmaxf(a, 0.0f);
    }
    if (isTgt) {
        float x = p[0], y = p[1], z = p[2];
        float4 v; v.x = x; v.y = y; v.z = z; v.w = x * x + y * y + z * z;
        ((float4*)tgt_m2)[b * NPTS + n] = v;
        float av[FF];
#pragma unroll
        for (int j = 0; j < FF; j++) av[j] = bd1[j];
#pragma unroll
        for (int i = 0; i < FF; i++) {
            float fi = ft[i];
#pragma unroll
            for (int j = 0; j < FF; j++)
                av[j] = fmaf(fi, Wd1[(3 + i) * FF + j], av[j]);
        }
#pragma unroll
        for (int j = 0; j < FF; j++) tgt_A[(b * NPTS + n) * FF + j] = av[j];
    } else {
#pragma unroll
        for (int j = 0; j < FF; j++) src_feat[(b * NPTS + n) * FF + j] = ft[j];
        float acc = bw2[0];
#pragma unroll
        for (int j = 0; j < 16; j++) {
            float a = bw1[j];
#pragma unroll
            for (int i = 0; i < FF; i++) a = fmaf(ft[i], Ww1[i * 16 + j], a);
            acc = fmaf(fmaxf(a, 0.0f), Ww2[j], acc);
        }
        score[b * NPTS + n] = acc;
    }
}

// ---------------- K2: rank-based top-K (exact lax.top_k order) ----------------
__global__ __launch_bounds__(256)
void k_rank(const float* __restrict__ score, const float* __restrict__ src_pts,
            const float* __restrict__ R,
            int* __restrict__ key_idx, float* __restrict__ kxyz,
            float* __restrict__ kxyz_t, float* __restrict__ out_kxyz)
{
    int blk = blockIdx.x;            // 0..BB*16-1
    int b = blk >> 4;
    int pbase = (blk & 15) << 6;     // 64 points per block
    int t = threadIdx.x;
    int sub = t & 3;                 // j-partition 0..3
    int lp = t >> 2;                 // local point 0..63
    int n = pbase + lp;
    __shared__ float sc[NPTS];
    for (int i = t; i < NPTS; i += 256) sc[i] = score[b * NPTS + i];
    __syncthreads();
    float s = sc[n];
    int rank = 0;
#pragma unroll 8
    for (int jj = 0; jj < 256; jj++) {
        int j = (jj << 2) | sub;
        float sj = sc[j];
        bool before = (sj > s) || (sj == s && j < n);
        rank += before ? 1 : 0;
    }
    rank += __shfl_xor(rank, 1, 64);
    rank += __shfl_xor(rank, 2, 64);
    if (sub == 0 && rank < KK) {
        key_idx[b * KK + rank] = n;
        float x = src_pts[(b * 6 + 0) * NPTS + n];
        float y = src_pts[(b * 6 + 1) * NPTS + n];
        float z = src_pts[(b * 6 + 2) * NPTS + n];
        int o = (b * KK + rank) * 3;
        kxyz[o] = x; kxyz[o + 1] = y; kxyz[o + 2] = z;
        out_kxyz[o] = x; out_kxyz[o + 1] = y; out_kxyz[o + 2] = z;
#pragma unroll
        for (int i = 0; i < 3; i++)
            kxyz_t[o + i] = R[i * 3 + 0] * x + R[i * 3 + 1] * y + R[i * 3 + 2] * z;
    }
}

// ---------------- K3: separable NN scan + gemb tail on r==0 blocks ----------------
__global__ __launch_bounds__(256)
void k_scan(const float* __restrict__ kxyz_t, const float* __restrict__ tgt_m2,
            const float* __restrict__ kxyz, const int* __restrict__ key_idx,
            const float* __restrict__ src_feat,
            const float* __restrict__ Wd1, const float* __restrict__ bd1,
            const float* __restrict__ Wd2, const float* __restrict__ bd2,
            float2* __restrict__ part, float* __restrict__ src_emb)
{
    int bid = blockIdx.x;
    int bk = bid >> 2, r = bid & 3;
    int b = bk >> 6, kk = bk & 63;
    int t = threadIdx.x;
    int u = t >> 7, lt = t & 127;
    __shared__ float4 P[256];            // 4 KB
    __shared__ float2 pbuf[2][NCOL][11]; // 21.3 KB
    __shared__ float kxs[KK][3];
    __shared__ int gidx[NSZ];
    __shared__ float hb[NSZ][FF + 1];    // +1 pad
    __shared__ float eb[NSZ][FF + 1];
    P[t] = ((const float4*)tgt_m2)[(b << 10) + (r << 8) + t];
    float kx = kxyz_t[bk * 3 + 0], ky = kxyz_t[bk * 3 + 1], kz = kxyz_t[bk * 3 + 2];
    float kx2 = -2.0f * kx, ky2 = -2.0f * ky, kz2 = -2.0f * kz;
    bool active = lt < NCOL;
    int pc = active ? lt : 0;
    int ixv = pc / 11, iyv = pc - ixv * 11;
    float gx2 = -2.0f * (-2.0f + ixv * 0.4f);
    float gy2 = -2.0f * (-2.0f + iyv * 0.4f);
    float gz2[11];
#pragma unroll
    for (int iz = 0; iz < 11; iz++) gz2[iz] = -2.0f * (-2.0f + iz * 0.4f);
    float best[11]; int bn[11];
#pragma unroll
    for (int iz = 0; iz < 11; iz++) { best[iz] = 3.0e38f; bn[iz] = 0; }
    __syncthreads();
    if (active) {
        const int pb = u << 7;           // unit scans 128 points
#pragma unroll 8
        for (int i = 0; i < 128; i++) {
            float4 v = P[pb + i];        // wave-uniform addr -> LDS broadcast
            float a = fmaf(kx2, v.x, fmaf(ky2, v.y, fmaf(kz2, v.z, v.w)));
            float e = fmaf(gx2, v.x, fmaf(gy2, v.y, a));
#pragma unroll
            for (int iz = 0; iz < 11; iz++) {
                float d = fmaf(gz2[iz], v.z, e);
                bool l = d < best[iz];   // strict <: first-min in scan order
                best[iz] = l ? d : best[iz];
                bn[iz] = l ? i : bn[iz];
            }
        }
#pragma unroll
        for (int iz = 0; iz < 11; iz++)
            pbuf[u][lt][iz] = make_float2(best[iz], __int_as_float(bn[iz] + (u << 7)));
    }
    __syncthreads();
    if (u == 0 && active) {
        int cbase = ((bk << 2) + r) * CC + lt * 11;  // c = p*11 + iz (contiguous)
#pragma unroll
        for (int iz = 0; iz < 11; iz++) {
            float2 r0 = pbuf[0][lt][iz], r1 = pbuf[1][lt][iz];
            float2 m = (r1.x < r0.x) ? r1 : r0;      // tie -> unit 0 = lower points
            part[cbase + iz] = make_float2(m.x,
                __int_as_float(__float_as_int(m.y) + (r << 8)));
        }
    }
    if (r != 0) return;                  // block-uniform: barriers below are safe
    // ---------------- gemb tail (verbatim, single producer) ------
    if (t < KK) {
        kxs[t][0] = kxyz[(b * KK + t) * 3 + 0];
        kxs[t][1] = kxyz[(b * KK + t) * 3 + 1];
        kxs[t][2] = kxyz[(b * KK + t) * 3 + 2];
    }
    __syncthreads();
    if (t < KK) {                        // wave 0: ballot grouping
        float cx = kxs[kk][0], cy = kxs[kk][1], cz = kxs[kk][2];
        float dx = kxs[t][0] - cx, dy = kxs[t][1] - cy, dz = kxs[t][2] - cz;
        float sq = dx * dx + dy * dy + dz * dz;
        unsigned long long mask = __ballot(sq <= RAD2);
        if (t < NSZ) {
            int cnt = __popcll(mask);
            int want = (t < cnt) ? t : 0;
            unsigned long long mm = mask;
            for (int q = 0; q < want; q++) mm &= (mm - 1);
            gidx[t] = __ffsll(mm) - 1;
        }
    }
    __syncthreads();
    {   // layer 1: 256 thr = 32 neighbors x 8 j-groups of 4
        int s = t >> 3, jb = (t & 7) << 2;
        int g = gidx[s];
        float cx = kxs[kk][0], cy = kxs[kk][1], cz = kxs[kk][2];
        float xr = kxs[g][0] - cx, yr = kxs[g][1] - cy, zr = kxs[g][2] - cz;
        int orig = key_idx[b * KK + g];
        const float* fz = &src_feat[(b * NPTS + orig) * FF];
        float fr[FF];
#pragma unroll
        for (int i = 0; i < FF; i++) fr[i] = fz[i];
#pragma unroll
        for (int jj = 0; jj < 4; jj++) {
            int j = jb + jj;
            float a = bd1[j];
            a = fmaf(xr, Wd1[0 * FF + j], a);
            a = fmaf(yr, Wd1[1 * FF + j], a);
            a = fmaf(zr, Wd1[2 * FF + j], a);
#pragma unroll
            for (int i = 0; i < FF; i++) a = fmaf(fr[i], Wd1[(3 + i) * FF + j], a);
            hb[s][j] = fmaxf(a, 0.0f);
        }
    }
    __syncthreads();
    {   // layer 2
        int s = t >> 3, jb = (t & 7) << 2;
#pragma unroll
        for (int jj = 0; jj < 4; jj++) {
            int j = jb + jj;
            float a = bd2[j];
#pragma unroll
            for (int i = 0; i < FF; i++) a = fmaf(hb[s][i], Wd2[i * FF + j], a);
            eb[s][j] = fmaxf(a, 0.0f);
        }
    }
    __syncthreads();
    if (t < FF) {                        // maxpool, ascending s (matches gemb)
        float m = eb[0][t];
#pragma unroll
        for (int s2 = 1; s2 < NSZ; s2++) m = fmaxf(m, eb[s2][t]);
        src_emb[bk * FF + t] = m;
    }
}

// ---------------- K4: merge -> gather A -> slim dfe -> sim -> chunk softmax partials
// 768 blocks x 256 thr. sim never leaves the block: per-chunk online-softmax
// partials (m_c, sum_e, sum_e*cx, sum_e*cy, sum_e*cz) -> chunkred[bk][chunk].
__global__ __launch_bounds__(256)
void k_mlp(const float2* __restrict__ part, const float* __restrict__ kxyz_t,
           const float* __restrict__ tgt_m2, const float* __restrict__ tgt_A,
           const float* __restrict__ src_emb,
           const float* __restrict__ Wd1,
           const float* __restrict__ Wd2, const float* __restrict__ bd2,
           float* __restrict__ chunkred)
{
    int bid = blockIdx.x;
    int chunk = bid % NCH;
    int bk = bid / NCH;
    int b = bk >> 6;
    int t = threadIdx.x;
    int c = chunk * 256 + t;
    int cc = min(c, CC - 1);
    float2 rb = part[(bk << 2) * CC + cc];
#pragma unroll
    for (int r = 1; r < NRNG; r++) {
        float2 o = part[((bk << 2) + r) * CC + cc];
        if (o.x < rb.x) rb = o;          // ascending r, strict <
    }
    int nb = __float_as_int(rb.y);
    float4 nv = ((const float4*)tgt_m2)[(b << 10) + nb];
    const float4* az = (const float4*)&tgt_A[((b << 10) + nb) * FF];
    float h[FF];
#pragma unroll
    for (int i = 0; i < FF / 4; i++) {
        float4 v = az[i];
        h[i * 4 + 0] = v.x; h[i * 4 + 1] = v.y; h[i * 4 + 2] = v.z; h[i * 4 + 3] = v.w;
    }
    int ixv = cc / 121, rem = cc - ixv * 121, iyv = rem / 11, izv = rem - iyv * 11;
    float cx = kxyz_t[bk * 3 + 0] + (-2.0f + ixv * 0.4f);
    float cy = kxyz_t[bk * 3 + 1] + (-2.0f + iyv * 0.4f);
    float cz = kxyz_t[bk * 3 + 2] + (-2.0f + izv * 0.4f);
    float x0 = cx - nv.x, x1 = cy - nv.y, x2 = cz - nv.z;
#pragma unroll
    for (int j = 0; j < FF; j++) {
        float a = h[j];
        a = fmaf(x0, Wd1[0 * FF + j], a);
        a = fmaf(x1, Wd1[1 * FF + j], a);
        a = fmaf(x2, Wd1[2 * FF + j], a);
        h[j] = fmaxf(a, 0.0f);
    }
    float sv = 0.0f;
#pragma unroll
    for (int j = 0; j < FF; j++) {
        float a = bd2[j];
#pragma unroll
        for (int i = 0; i < FF; i++) a = fmaf(h[i], Wd2[i * FF + j], a);
        sv = fmaf(fmaxf(a, 0.0f), src_emb[bk * FF + j], sv);
    }
    // ---- per-chunk online-softmax partials (no global sim) ----
    bool valid = (c < CC);
    __shared__ float red[256];
    __shared__ float4 red4[256];
    red[t] = valid ? sv : -3.0e38f;
    __syncthreads();
    for (int s2 = 128; s2 > 0; s2 >>= 1) {
        if (t < s2) red[t] = fmaxf(red[t], red[t + s2]);
        __syncthreads();
    }
    float mc = red[0];
    float e = valid ? expf(sv - mc) : 0.0f;
    red4[t] = make_float4(e, e * cx, e * cy, e * cz);
    __syncthreads();
    for (int s2 = 128; s2 > 0; s2 >>= 1) {
        if (t < s2) {
            float4 a2 = red4[t], bq = red4[t + s2];
            red4[t] = make_float4(a2.x + bq.x, a2.y + bq.y, a2.z + bq.z, a2.w + bq.w);
        }
        __syncthreads();
    }
    if (t == 0) {
        float4 rr = red4[0];
        float* o = &chunkred[(bk * NCH + chunk) * 8];
        o[0] = mc; o[1] = rr.x; o[2] = rr.y; o[3] = rr.z; o[4] = rr.w;
    }
}

// ---------------- K5: merge 6 chunk partials per bk -> vcp ----------------
__global__ __launch_bounds__(64)
void k_final(const float* __restrict__ chunkred, float* __restrict__ out_vcp)
{
    int bk = blockIdx.x * 64 + threadIdx.x;   // grid 2 x 64 = 128
    if (bk >= BB * KK) return;
    const float* cr = &chunkred[bk * NCH * 8];
    float m = cr[0];
#pragma unroll
    for (int q = 1; q < NCH; q++) m = fmaxf(m, cr[q * 8]);
    float S = 0.f, X = 0.f, Y = 0.f, Z = 0.f;
#pragma unroll
    for (int q = 0; q < NCH; q++) {
        float w = expf(cr[q * 8] - m);
        S = fmaf(cr[q * 8 + 1], w, S);
        X = fmaf(cr[q * 8 + 2], w, X);
        Y = fmaf(cr[q * 8 + 3], w, Y);
        Z = fmaf(cr[q * 8 + 4], w, Z);
    }
    out_vcp[bk * 3 + 0] = X / S;
    out_vcp[bk * 3 + 1] = Y / S;
    out_vcp[bk * 3 + 2] = Z / S;
}

extern "C" void kernel_launch(void* const* d_in, const int* in_sizes, int n_in,
                              void* d_out, int out_size, void* d_ws, size_t ws_size,
                              hipStream_t stream)
{
    (void)in_sizes; (void)n_in; (void)out_size; (void)ws_size;
    const float* src_pts = (const float*)d_in[0];
    const float* tgt_pts = (const float*)d_in[1];
    const float* R_init  = (const float*)d_in[2];
    const float* W1  = (const float*)d_in[4];
    const float* b1  = (const float*)d_in[5];
    const float* W2  = (const float*)d_in[6];
    const float* b2  = (const float*)d_in[7];
    const float* Ww1 = (const float*)d_in[8];
    const float* bw1 = (const float*)d_in[9];
    const float* Ww2 = (const float*)d_in[10];
    const float* bw2 = (const float*)d_in[11];
    const float* Wd1 = (const float*)d_in[12];
    const float* bd1 = (const float*)d_in[13];
    const float* Wd2 = (const float*)d_in[14];
    const float* bd2 = (const float*)d_in[15];

    float* ws = (float*)d_ws;
    float* src_feat = ws;                              // 65536
    float* tgt_A    = src_feat + BB * NPTS * FF;       // 65536
    float* tgt_m2   = tgt_A + BB * NPTS * FF;          // 8192
    float* score    = tgt_m2 + BB * NPTS * 4;          // 2048
    int*   key_idx  = (int*)(score + BB * NPTS);       // 128
    float* kxyz     = (float*)(key_idx + BB * KK);     // 384
    float* kxyz_t   = kxyz + BB * KK * 3;              // 384
    float* src_emb  = kxyz_t + BB * KK * 3;            // 4096
    float* chunkred = src_emb + BB * KK * FF;          // 128*6*8 = 6144
    float2* part    = (float2*)(chunkred + BB * KK * NCH * 8); // 5.45 MB

    float* out_kxyz = (float*)d_out;
    float* out_vcp  = out_kxyz + BB * KK * 3;

    k_features<<<64, 64, 0, stream>>>(
        src_pts, tgt_pts, W1, b1, W2, b2, Ww1, bw1, Ww2, bw2, Wd1, bd1,
        src_feat, tgt_A, tgt_m2, score);
    k_rank<<<BB * 16, 256, 0, stream>>>(score, src_pts, R_init,
                                        key_idx, kxyz, kxyz_t, out_kxyz);
    k_scan<<<BB * KK * NRNG, 256, 0, stream>>>(kxyz_t, tgt_m2, kxyz, key_idx,
                                               src_feat, Wd1, bd1, Wd2, bd2,
                                               part, src_emb);
    k_mlp<<<BB * KK * NCH, 256, 0, stream>>>(part, kxyz_t, tgt_m2, tgt_A, src_emb,
                                             Wd1, Wd2, bd2, chunkred);
    k_final<<<2, 64, 0, stream>>>(chunkred, out_vcp);
}